// Round 1
// baseline (85.544 us; speedup 1.0000x reference)
//
#include <hip/hip_runtime.h>

#define WAVE 64

__global__ void hs_init(double* ws) {
    if (threadIdx.x == 0) { ws[0] = 0.0; ws[1] = 0.0; }
}

__global__ __launch_bounds__(256) void hs_main(
    const float* __restrict__ emb,        // [N, 256]
    const float* __restrict__ fc,         // [V-1, 256]
    const int*   __restrict__ target,     // [N]
    const int*   __restrict__ path_idx,   // [V, L]
    const float* __restrict__ path_codes, // [V, L]
    const float* __restrict__ path_mask,  // [V, L]
    double* __restrict__ ws,
    int N, int L)
{
    const int lane   = threadIdx.x & (WAVE - 1);
    const int wid    = threadIdx.x >> 6;                       // wave id in block
    const int gwave  = (blockIdx.x * blockDim.x + threadIdx.x) >> 6;
    const int nwaves = (gridDim.x * blockDim.x) >> 6;

    float local_bce = 0.0f;
    float local_cnt = 0.0f;

    for (int row = gwave; row < N; row += nwaves) {
        const float4 e = *reinterpret_cast<const float4*>(emb + (size_t)row * 256 + lane * 4);
        const int t = target[row];
        const int*   pi = path_idx   + (size_t)t * L;
        const float* pc = path_codes + (size_t)t * L;
        const float* pm = path_mask  + (size_t)t * L;

        for (int l = 0; l < L; ++l) {
            const float m = pm[l];           // broadcast load (all lanes same addr)
            if (m == 0.0f) break;            // mask is a prefix -> wave-uniform
            const int node = pi[l];
            const float4 w = *reinterpret_cast<const float4*>(fc + (size_t)node * 256 + lane * 4);
            float p = e.x * w.x + e.y * w.y + e.z * w.z + e.w * w.w;
            // wave-64 tree reduction -> lane 0
            #pragma unroll
            for (int off = 32; off > 0; off >>= 1)
                p += __shfl_down(p, off, WAVE);
            if (lane == 0) {
                const float y = pc[l];
                // stable bce_with_logits: max(x,0) - x*y + log1p(exp(-|x|))
                const float bce = fmaxf(p, 0.0f) - p * y + log1pf(expf(-fabsf(p)));
                local_bce += bce;
                local_cnt += 1.0f;
            }
        }
    }

    // block reduction: lane 0 of each wave contributes
    __shared__ float s_bce[4];
    __shared__ float s_cnt[4];
    if (lane == 0) { s_bce[wid] = local_bce; s_cnt[wid] = local_cnt; }
    __syncthreads();
    if (threadIdx.x == 0) {
        float b = 0.0f, c = 0.0f;
        const int nw = blockDim.x >> 6;
        for (int i = 0; i < nw; ++i) { b += s_bce[i]; c += s_cnt[i]; }
        atomicAdd(&ws[0], (double)b);
        atomicAdd(&ws[1], (double)c);
    }
}

__global__ void hs_fin(const double* __restrict__ ws, float* __restrict__ out) {
    if (threadIdx.x == 0) out[0] = (float)(ws[0] / ws[1]);
}

extern "C" void kernel_launch(void* const* d_in, const int* in_sizes, int n_in,
                              void* d_out, int out_size, void* d_ws, size_t ws_size,
                              hipStream_t stream) {
    const float* emb        = (const float*)d_in[0];   // [64,1,128,256]
    const float* fc         = (const float*)d_in[1];   // [V-1, 256]
    const int*   target     = (const int*)d_in[2];     // [64,1,128]
    const int*   path_idx   = (const int*)d_in[3];     // [V, L]
    const float* path_codes = (const float*)d_in[4];   // [V, L]
    const float* path_mask  = (const float*)d_in[5];   // [V, L]

    const int N = in_sizes[2];                 // 8192 targets
    const int V = in_sizes[1] / 256 + 1;       // vocab (fc has V-1 rows of 256)
    const int L = in_sizes[3] / V;             // padded path length

    double* ws  = (double*)d_ws;
    float*  out = (float*)d_out;

    hs_init<<<1, 64, 0, stream>>>(ws);

    const int block = 256;                      // 4 waves/block
    const int waves_needed = N;                 // one wave per row
    int grid = (waves_needed * WAVE + block - 1) / block;   // 2048 blocks
    if (grid < 1) grid = 1;
    hs_main<<<grid, block, 0, stream>>>(emb, fc, target, path_idx, path_codes,
                                        path_mask, ws, N, L);

    hs_fin<<<1, 64, 0, stream>>>(ws, out);
}

// Round 2
// 84.933 us; speedup vs baseline: 1.0072x; 1.0072x over previous
//
#include <hip/hip_runtime.h>

#define WAVE 64
#define CHUNK 8

__global__ void hs_init(double* ws) {
    if (threadIdx.x == 0) { ws[0] = 0.0; ws[1] = 0.0; }
}

__global__ __launch_bounds__(256) void hs_main(
    const float* __restrict__ emb,        // [N, 256]
    const float* __restrict__ fc,         // [V-1, 256]
    const int*   __restrict__ target,     // [N]
    const int*   __restrict__ path_idx,   // [V, L]
    const float* __restrict__ path_codes, // [V, L]
    const float* __restrict__ path_mask,  // [V, L]
    double* __restrict__ ws,
    int N, int L)
{
    const int lane   = threadIdx.x & (WAVE - 1);
    const int wid    = threadIdx.x >> 6;
    const int gwave  = (blockIdx.x * blockDim.x + threadIdx.x) >> 6;
    const int nwaves = (gridDim.x * blockDim.x) >> 6;

    float bce_acc = 0.0f;   // identical on all lanes of a wave
    float cnt_acc = 0.0f;

    for (int row = gwave; row < N; row += nwaves) {
        const float4 e = *reinterpret_cast<const float4*>(emb + (size_t)row * 256 + lane * 4);
        const int t = target[row];

        // prefetch the whole path's metadata: lane l holds entry l (coalesced)
        int   my_pi = 0;
        float my_pc = 0.0f;
        float my_pm = 0.0f;
        if (lane < L) {
            const size_t off = (size_t)t * L + lane;
            my_pi = path_idx[off];
            my_pc = path_codes[off];
            my_pm = path_mask[off];
        }
        const unsigned long long bal = __ballot(my_pm != 0.0f);
        const int plen = __popcll(bal);       // mask is a prefix
        cnt_acc += (float)plen;

        for (int base = 0; base < plen; base += CHUNK) {
            int c = plen - base; if (c > CHUNK) c = CHUNK;

            // issue all gathers first: 8-deep memory-level parallelism
            float4 w[CHUNK];
            #pragma unroll
            for (int k = 0; k < CHUNK; ++k) {
                if (k < c) {
                    const int node = __shfl(my_pi, base + k, WAVE);
                    w[k] = *reinterpret_cast<const float4*>(fc + (size_t)node * 256 + lane * 4);
                }
            }

            float part[CHUNK];
            #pragma unroll
            for (int k = 0; k < CHUNK; ++k)
                if (k < c)
                    part[k] = e.x * w[k].x + e.y * w[k].y + e.z * w[k].z + e.w * w[k].w;

            // 8 independent butterfly reductions — stages pipeline across k
            #pragma unroll
            for (int off = 32; off > 0; off >>= 1) {
                #pragma unroll
                for (int k = 0; k < CHUNK; ++k)
                    if (k < c)
                        part[k] += __shfl_xor(part[k], off, WAVE);
            }

            // all lanes hold the full dot; compute BCE redundantly (no divergence)
            #pragma unroll
            for (int k = 0; k < CHUNK; ++k) {
                if (k < c) {
                    const float y = __shfl(my_pc, base + k, WAVE);
                    const float p = part[k];
                    bce_acc += fmaxf(p, 0.0f) - p * y + log1pf(__expf(-fabsf(p)));
                }
            }
        }
    }

    // block reduction: lane 0 of each wave contributes its wave's (identical) sums
    __shared__ float s_bce[4];
    __shared__ float s_cnt[4];
    if (lane == 0) { s_bce[wid] = bce_acc; s_cnt[wid] = cnt_acc; }
    __syncthreads();
    if (threadIdx.x == 0) {
        float b = 0.0f, cc = 0.0f;
        const int nw = blockDim.x >> 6;
        for (int i = 0; i < nw; ++i) { b += s_bce[i]; cc += s_cnt[i]; }
        atomicAdd(&ws[0], (double)b);
        atomicAdd(&ws[1], (double)cc);
    }
}

__global__ void hs_fin(const double* __restrict__ ws, float* __restrict__ out) {
    if (threadIdx.x == 0) out[0] = (float)(ws[0] / ws[1]);
}

extern "C" void kernel_launch(void* const* d_in, const int* in_sizes, int n_in,
                              void* d_out, int out_size, void* d_ws, size_t ws_size,
                              hipStream_t stream) {
    const float* emb        = (const float*)d_in[0];
    const float* fc         = (const float*)d_in[1];
    const int*   target     = (const int*)d_in[2];
    const int*   path_idx   = (const int*)d_in[3];
    const float* path_codes = (const float*)d_in[4];
    const float* path_mask  = (const float*)d_in[5];

    const int N = in_sizes[2];
    const int V = in_sizes[1] / 256 + 1;
    const int L = in_sizes[3] / V;

    double* ws  = (double*)d_ws;
    float*  out = (float*)d_out;

    hs_init<<<1, 64, 0, stream>>>(ws);

    const int block = 256;
    int grid = (N * WAVE + block - 1) / block;   // one wave per row
    if (grid < 1) grid = 1;
    hs_main<<<grid, block, 0, stream>>>(emb, fc, target, path_idx, path_codes,
                                        path_mask, ws, N, L);

    hs_fin<<<1, 64, 0, stream>>>(ws, out);
}

// Round 3
// 54.804 us; speedup vs baseline: 1.5609x; 1.5497x over previous
//
#include <hip/hip_runtime.h>

#define WAVE 64
#define CHUNK 8

__global__ __launch_bounds__(256) void hs_main(
    const float* __restrict__ emb,        // [N, 256]
    const float* __restrict__ fc,         // [V-1, 256]
    const int*   __restrict__ target,     // [N]
    const int*   __restrict__ path_idx,   // [V, L]
    const float* __restrict__ path_codes, // [V, L]
    const float* __restrict__ path_mask,  // [V, L]
    float2* __restrict__ partials,        // [gridDim.x]
    int N, int L)
{
    const int lane   = threadIdx.x & (WAVE - 1);
    const int wid    = threadIdx.x >> 6;
    const int gwave  = (blockIdx.x * blockDim.x + threadIdx.x) >> 6;
    const int nwaves = (gridDim.x * blockDim.x) >> 6;

    float bce_acc = 0.0f;   // identical on all lanes of a wave
    float cnt_acc = 0.0f;

    for (int row = gwave; row < N; row += nwaves) {
        const float4 e = *reinterpret_cast<const float4*>(emb + (size_t)row * 256 + lane * 4);
        const int t = target[row];

        // prefetch the whole path's metadata: lane l holds entry l (coalesced)
        int   my_pi = 0;
        float my_pc = 0.0f;
        float my_pm = 0.0f;
        if (lane < L) {
            const size_t off = (size_t)t * L + lane;
            my_pi = path_idx[off];
            my_pc = path_codes[off];
            my_pm = path_mask[off];
        }
        const unsigned long long bal = __ballot(my_pm != 0.0f);
        const int plen = __popcll(bal);       // mask is a prefix
        cnt_acc += (float)plen;

        for (int base = 0; base < plen; base += CHUNK) {
            int c = plen - base; if (c > CHUNK) c = CHUNK;

            // issue all gathers first: 8-deep memory-level parallelism
            float4 w[CHUNK];
            #pragma unroll
            for (int k = 0; k < CHUNK; ++k) {
                if (k < c) {
                    const int node = __shfl(my_pi, base + k, WAVE);
                    w[k] = *reinterpret_cast<const float4*>(fc + (size_t)node * 256 + lane * 4);
                }
            }

            float part[CHUNK];
            #pragma unroll
            for (int k = 0; k < CHUNK; ++k)
                if (k < c)
                    part[k] = e.x * w[k].x + e.y * w[k].y + e.z * w[k].z + e.w * w[k].w;

            // independent butterfly reductions — stages pipeline across k
            #pragma unroll
            for (int off = 32; off > 0; off >>= 1) {
                #pragma unroll
                for (int k = 0; k < CHUNK; ++k)
                    if (k < c)
                        part[k] += __shfl_xor(part[k], off, WAVE);
            }

            // all lanes hold the full dot; compute BCE redundantly (no divergence)
            #pragma unroll
            for (int k = 0; k < CHUNK; ++k) {
                if (k < c) {
                    const float y = __shfl(my_pc, base + k, WAVE);
                    const float p = part[k];
                    bce_acc += fmaxf(p, 0.0f) - p * y + log1pf(__expf(-fabsf(p)));
                }
            }
        }
    }

    // block reduction -> one float2 per block, NO atomics
    __shared__ float s_bce[4];
    __shared__ float s_cnt[4];
    if (lane == 0) { s_bce[wid] = bce_acc; s_cnt[wid] = cnt_acc; }
    __syncthreads();
    if (threadIdx.x == 0) {
        float b = 0.0f, cc = 0.0f;
        const int nw = blockDim.x >> 6;
        for (int i = 0; i < nw; ++i) { b += s_bce[i]; cc += s_cnt[i]; }
        partials[blockIdx.x] = make_float2(b, cc);
    }
}

__global__ __launch_bounds__(256) void hs_fin(
    const float2* __restrict__ partials, int nparts, float* __restrict__ out)
{
    double b = 0.0, c = 0.0;
    for (int i = threadIdx.x; i < nparts; i += blockDim.x) {
        const float2 p = partials[i];
        b += (double)p.x;
        c += (double)p.y;
    }
    __shared__ double sb[256], sc[256];
    sb[threadIdx.x] = b; sc[threadIdx.x] = c;
    __syncthreads();
    for (int s = 128; s > 0; s >>= 1) {
        if (threadIdx.x < s) {
            sb[threadIdx.x] += sb[threadIdx.x + s];
            sc[threadIdx.x] += sc[threadIdx.x + s];
        }
        __syncthreads();
    }
    if (threadIdx.x == 0) out[0] = (float)(sb[0] / sc[0]);
}

extern "C" void kernel_launch(void* const* d_in, const int* in_sizes, int n_in,
                              void* d_out, int out_size, void* d_ws, size_t ws_size,
                              hipStream_t stream) {
    const float* emb        = (const float*)d_in[0];
    const float* fc         = (const float*)d_in[1];
    const int*   target     = (const int*)d_in[2];
    const int*   path_idx   = (const int*)d_in[3];
    const float* path_codes = (const float*)d_in[4];
    const float* path_mask  = (const float*)d_in[5];

    const int N = in_sizes[2];
    const int V = in_sizes[1] / 256 + 1;
    const int L = in_sizes[3] / V;

    float2* partials = (float2*)d_ws;
    float*  out      = (float*)d_out;

    const int block = 256;
    int grid = (N * WAVE + block - 1) / block;   // one wave per row -> 2048 blocks
    if (grid < 1) grid = 1;
    if ((size_t)grid * sizeof(float2) > ws_size)  // safety: clamp to workspace
        grid = (int)(ws_size / sizeof(float2));

    hs_main<<<grid, block, 0, stream>>>(emb, fc, target, path_idx, path_codes,
                                        path_mask, partials, N, L);
    hs_fin<<<1, block, 0, stream>>>(partials, grid, out);
}

// Round 4
// 28.238 us; speedup vs baseline: 3.0294x; 1.9408x over previous
//
#include <hip/hip_runtime.h>

#define WAVE 64
#define CHUNK 8

__global__ __launch_bounds__(256) void hs_main(
    const float* __restrict__ emb,        // [N, 256]
    const float* __restrict__ fc,         // [V-1, 256]
    const int*   __restrict__ target,     // [N]
    const int*   __restrict__ path_idx,   // [V, L]
    const float* __restrict__ path_codes, // [V, L]
    const float* __restrict__ path_mask,  // [V, L]
    float2* __restrict__ partials,        // [gridDim.x]
    int N, int L)
{
    const int lane   = threadIdx.x & (WAVE - 1);
    const int wid    = threadIdx.x >> 6;
    const int gwave  = (blockIdx.x * blockDim.x + threadIdx.x) >> 6;
    const int nwaves = (gridDim.x * blockDim.x) >> 6;

    float bce_acc = 0.0f;   // identical on all lanes of a wave
    float cnt_acc = 0.0f;

    for (int row = gwave; row < N; row += nwaves) {
        const float4 e = *reinterpret_cast<const float4*>(emb + (size_t)row * 256 + lane * 4);
        const int t = target[row];

        // path metadata: lane l holds entry l (coalesced); padded entries are 0
        int   my_pi = 0;
        float my_pc = 0.0f;
        float my_pm = 0.0f;
        if (lane < L) {
            const size_t off = (size_t)t * L + lane;
            my_pi = path_idx[off];
            my_pc = path_codes[off];
            my_pm = path_mask[off];
        }
        const unsigned long long bal = __ballot(my_pm != 0.0f);
        const int plen = __popcll(bal);       // mask is a prefix, plen <= 64
        cnt_acc += (float)plen;

        for (int base = 0; base < plen; base += CHUNK) {
            // --- phase 1: broadcast 8 node ids (independent bpermutes) ---
            int node[CHUNK];
            #pragma unroll
            for (int k = 0; k < CHUNK; ++k)
                node[k] = __shfl(my_pi, base + k, WAVE);   // pad -> 0 (safe row)

            // --- phase 2: 8 unconditional gathers, grouped => real MLP=8 ---
            float4 w[CHUNK];
            #pragma unroll
            for (int k = 0; k < CHUNK; ++k)
                w[k] = *reinterpret_cast<const float4*>(fc + (size_t)node[k] * 256 + lane * 4);

            // --- phase 3: codes broadcast overlaps gather latency ---
            float y[CHUNK];
            #pragma unroll
            for (int k = 0; k < CHUNK; ++k)
                y[k] = __shfl(my_pc, base + k, WAVE);

            // --- phase 4: dots ---
            float part[CHUNK];
            #pragma unroll
            for (int k = 0; k < CHUNK; ++k)
                part[k] = e.x * w[k].x + e.y * w[k].y + e.z * w[k].z + e.w * w[k].w;

            // --- phase 5: 8 independent butterflies, stages interleave ---
            #pragma unroll
            for (int off = 32; off > 0; off >>= 1) {
                #pragma unroll
                for (int k = 0; k < CHUNK; ++k)
                    part[k] += __shfl_xor(part[k], off, WAVE);
            }

            // --- phase 6: BCE on all lanes, arithmetic mask (no loads) ---
            #pragma unroll
            for (int k = 0; k < CHUNK; ++k) {
                const float m = (base + k < plen) ? 1.0f : 0.0f;
                const float p = part[k];
                const float bce = fmaxf(p, 0.0f) - p * y[k]
                                + __logf(1.0f + __expf(-fabsf(p)));
                bce_acc += m * bce;
            }
        }
    }

    // block reduction -> one float2 per block, NO atomics
    __shared__ float s_bce[4];
    __shared__ float s_cnt[4];
    if (lane == 0) { s_bce[wid] = bce_acc; s_cnt[wid] = cnt_acc; }
    __syncthreads();
    if (threadIdx.x == 0) {
        float b = 0.0f, cc = 0.0f;
        const int nw = blockDim.x >> 6;
        for (int i = 0; i < nw; ++i) { b += s_bce[i]; cc += s_cnt[i]; }
        partials[blockIdx.x] = make_float2(b, cc);
    }
}

__global__ __launch_bounds__(256) void hs_fin(
    const float2* __restrict__ partials, int nparts, float* __restrict__ out)
{
    double b = 0.0, c = 0.0;
    for (int i = threadIdx.x; i < nparts; i += blockDim.x) {
        const float2 p = partials[i];
        b += (double)p.x;
        c += (double)p.y;
    }
    __shared__ double sb[256], sc[256];
    sb[threadIdx.x] = b; sc[threadIdx.x] = c;
    __syncthreads();
    for (int s = 128; s > 0; s >>= 1) {
        if (threadIdx.x < s) {
            sb[threadIdx.x] += sb[threadIdx.x + s];
            sc[threadIdx.x] += sc[threadIdx.x + s];
        }
        __syncthreads();
    }
    if (threadIdx.x == 0) out[0] = (float)(sb[0] / sc[0]);
}

extern "C" void kernel_launch(void* const* d_in, const int* in_sizes, int n_in,
                              void* d_out, int out_size, void* d_ws, size_t ws_size,
                              hipStream_t stream) {
    const float* emb        = (const float*)d_in[0];
    const float* fc         = (const float*)d_in[1];
    const int*   target     = (const int*)d_in[2];
    const int*   path_idx   = (const int*)d_in[3];
    const float* path_codes = (const float*)d_in[4];
    const float* path_mask  = (const float*)d_in[5];

    const int N = in_sizes[2];
    const int V = in_sizes[1] / 256 + 1;
    const int L = in_sizes[3] / V;

    float2* partials = (float2*)d_ws;
    float*  out      = (float*)d_out;

    const int block = 256;
    int grid = (N * WAVE + block - 1) / block;   // one wave per row -> 2048 blocks
    if (grid < 1) grid = 1;
    if ((size_t)grid * sizeof(float2) > ws_size)
        grid = (int)(ws_size / sizeof(float2));

    hs_main<<<grid, block, 0, stream>>>(emb, fc, target, path_idx, path_codes,
                                        path_mask, partials, N, L);
    hs_fin<<<1, block, 0, stream>>>(partials, grid, out);
}